// Round 1
// baseline (640.759 us; speedup 1.0000x reference)
//
#include <hip/hip_runtime.h>

#define W    320
#define CC   128
#define TJ   64
#define NR   128          // Rt rows: k in [j0-63, j0+64]
#define LSTR 136          // LDS row stride (bf16 elems): 128 + 8 pad -> 272 B

typedef __attribute__((ext_vector_type(8))) short   short8;
typedef __attribute__((ext_vector_type(4))) float   floatx4;

__device__ __forceinline__ unsigned short f2bf(float f) {
    // round-to-nearest-even fp32 -> bf16 (inputs are finite normals)
    unsigned int u = __float_as_uint(f);
    u += 0x7FFFu + ((u >> 16) & 1u);
    return (unsigned short)(u >> 16);
}

__global__ __launch_bounds__(256)
void cost_volume_kernel(const float* __restrict__ Lg,
                        const float* __restrict__ Rg,
                        float* __restrict__ out) {
    __shared__ unsigned short Lt[TJ * LSTR];   // 17 KB
    __shared__ unsigned short Rt[NR * LSTR];   // 34 KB

    const int jt  = blockIdx.x;       // 0..4
    const int bh  = blockIdx.y;       // 0..1279
    const int j0  = jt * TJ;
    const int tid = threadIdx.x;

    const int rsub = tid >> 5;        // 0..7  (row within pass)
    const int c4   = (tid & 31) << 2; // 0..124 (4 floats per thread per row)

    // ---- stage L: 64 rows x 128 c, fp32 -> bf16 ----
    const float* Lbase = Lg + (size_t)(bh * W + j0) * CC;
    #pragma unroll
    for (int p = 0; p < 8; ++p) {
        const int row = p * 8 + rsub;
        floatx4 v = *(const floatx4*)(Lbase + row * CC + c4);
        unsigned int lo = (unsigned int)f2bf(v.x) | ((unsigned int)f2bf(v.y) << 16);
        unsigned int hi = (unsigned int)f2bf(v.z) | ((unsigned int)f2bf(v.w) << 16);
        *(uint2*)&Lt[row * LSTR + c4] = make_uint2(lo, hi);
    }

    // ---- stage R: 128 rows (k = j0-63+row), zero-fill out-of-range k ----
    const float* Rrow0 = Rg + (size_t)(bh * W) * CC;
    #pragma unroll
    for (int p = 0; p < 16; ++p) {
        const int row = p * 8 + rsub;
        const int k = j0 - 63 + row;
        floatx4 v;
        v.x = 0.f; v.y = 0.f; v.z = 0.f; v.w = 0.f;
        if (k >= 0 && k < W) v = *(const floatx4*)(Rrow0 + (size_t)k * CC + c4);
        unsigned int lo = (unsigned int)f2bf(v.x) | ((unsigned int)f2bf(v.y) << 16);
        unsigned int hi = (unsigned int)f2bf(v.z) | ((unsigned int)f2bf(v.w) << 16);
        *(uint2*)&Rt[row * LSTR + c4] = make_uint2(lo, hi);
    }

    __syncthreads();

    const int lane = tid & 63;
    const int wave = tid >> 6;        // 0..3 -> m-tile
    const int col  = lane & 15;
    const int quad = lane >> 4;
    const int m0   = wave * 16;

    floatx4 acc[6];
    #pragma unroll
    for (int t = 0; t < 6; ++t) { acc[t].x = 0.f; acc[t].y = 0.f; acc[t].z = 0.f; acc[t].w = 0.f; }

    // C[m][n] = sum_c Lt[m][c] * Rt[n][c]; wave w covers n-tiles w..w+5 (cap 8)
    #pragma unroll
    for (int ks = 0; ks < 4; ++ks) {
        const short8 af = *(const short8*)&Lt[(m0 + col) * LSTR + ks * 32 + quad * 8];
        #pragma unroll
        for (int t = 0; t < 6; ++t) {
            const int nt = wave + t;
            if (nt < 8) {
                const short8 bf = *(const short8*)&Rt[(nt * 16 + col) * LSTR + ks * 32 + quad * 8];
                acc[t] = __builtin_amdgcn_mfma_f32_16x16x32_bf16(af, bf, acc[t], 0, 0, 0);
            }
        }
    }

    // ---- epilogue: C/D layout col=lane&15, row=quad*4+reg; i = m + 63 - n ----
    float* obase = out + (size_t)(bh * W + j0) * 64;
    #pragma unroll
    for (int t = 0; t < 6; ++t) {
        const int nt = wave + t;
        if (nt >= 8) continue;
        const int n = nt * 16 + col;
        #pragma unroll
        for (int r = 0; r < 4; ++r) {
            const int m = m0 + quad * 4 + r;
            const int i = m + 63 - n;
            if (i >= 0 && i < 64) {
                obase[m * 64 + i] = acc[t][r] * 0.0078125f;  // * 1/128 (mean over c)
            }
        }
    }
}

extern "C" void kernel_launch(void* const* d_in, const int* in_sizes, int n_in,
                              void* d_out, int out_size, void* d_ws, size_t ws_size,
                              hipStream_t stream) {
    const float* L = (const float*)d_in[0];
    const float* R = (const float*)d_in[1];
    float* out = (float*)d_out;
    dim3 grid(W / TJ, 8 * 160);   // (5, 1280)
    cost_volume_kernel<<<grid, 256, 0, stream>>>(L, R, out);
}

// Round 2
// 431.626 us; speedup vs baseline: 1.4845x; 1.4845x over previous
//
#include <hip/hip_runtime.h>

#define W  320
#define TJ 64

typedef __attribute__((ext_vector_type(8))) short   short8;
typedef __attribute__((ext_vector_type(4))) float   floatx4;

__device__ __forceinline__ unsigned short f2bf(float f) {
    // round-to-nearest-even fp32 -> bf16
    unsigned int u = __float_as_uint(f);
    u += 0x7FFFu + ((u >> 16) & 1u);
    return (unsigned short)(u >> 16);
}

// LDS layout: rows of 128 shorts (256 B), no pad. Conflict-free via XOR
// swizzle of the 16-B chunk index: chunk' = chunk ^ (row & 15).
// Lt = rows 0..63 (j0..j0+63), Rt = rows 64..191 (k = j0-63+rr).
__global__ __launch_bounds__(512, 6)
void cost_volume_kernel(const float* __restrict__ Lg,
                        const float* __restrict__ Rg,
                        float* __restrict__ out) {
    __shared__ unsigned short S[(64 + 128) * 128];   // 48 KB

    const int jt  = blockIdx.x;
    const int bh  = blockIdx.y;
    const int j0  = jt * TJ;
    const int tid = threadIdx.x;

    // staging decomposition: 32 threads per row, 4 floats each
    const int lr    = tid >> 5;          // 0..15 rows per pass
    const int half  = tid & 1;           // which 8-B half of a 16-B chunk
    const int chunk = (tid & 31) >> 1;   // 0..15
    const int cf    = (tid & 31) << 2;   // float offset 0..124

    // ---- stage L: 64 rows, 4 passes ----
    const float* Lbase = Lg + (size_t)(bh * W + j0) * 128;
    #pragma unroll
    for (int p = 0; p < 4; ++p) {
        const int row = p * 16 + lr;
        floatx4 v = *(const floatx4*)(Lbase + (size_t)row * 128 + cf);
        uint2 d;
        d.x = (unsigned)f2bf(v.x) | ((unsigned)f2bf(v.y) << 16);
        d.y = (unsigned)f2bf(v.z) | ((unsigned)f2bf(v.w) << 16);
        const int sw = chunk ^ (row & 15);
        *(uint2*)&S[row * 128 + (sw << 3) + half * 4] = d;
    }

    // ---- stage R: 128 rows (k = j0-63+rr), zero-fill OOB ----
    const float* Rrow0 = Rg + (size_t)(bh * W) * 128;
    #pragma unroll
    for (int p = 0; p < 8; ++p) {
        const int rr = p * 16 + lr;
        const int k  = j0 - 63 + rr;
        floatx4 v;
        v.x = 0.f; v.y = 0.f; v.z = 0.f; v.w = 0.f;
        if (k >= 0 && k < W) v = *(const floatx4*)(Rrow0 + (size_t)k * 128 + cf);
        uint2 d;
        d.x = (unsigned)f2bf(v.x) | ((unsigned)f2bf(v.y) << 16);
        d.y = (unsigned)f2bf(v.z) | ((unsigned)f2bf(v.w) << 16);
        const int sw = chunk ^ (rr & 15);
        *(uint2*)&S[(64 + rr) * 128 + (sw << 3) + half * 4] = d;
    }

    __syncthreads();

    // ---- MFMA band: 8 waves; wave = (mt, half-of-5-n-tiles) ----
    const int wave = tid >> 6;           // 0..7
    const int lane = tid & 63;
    const int col  = lane & 15;
    const int quad = lane >> 4;
    const int mt   = wave >> 1;          // 0..3
    const int g    = wave & 1;
    const int m0   = mt * 16;
    const int ntb  = mt + g * 3;         // g=0: {mt,mt+1,mt+2}; g=1: {mt+3,mt+4}
    const int NT   = g ? 2 : 3;

    floatx4 acc[3];
    #pragma unroll
    for (int t = 0; t < 3; ++t) { acc[t].x = 0.f; acc[t].y = 0.f; acc[t].z = 0.f; acc[t].w = 0.f; }

    #pragma unroll
    for (int ks = 0; ks < 4; ++ks) {
        // A row = m0+col; swizzled chunk = (ks*4+quad) ^ col (row&15 == col)
        const int sc = (ks * 4 + quad) ^ col;
        const short8 af = *(const short8*)&S[(m0 + col) * 128 + (sc << 3)];
        #pragma unroll
        for (int t = 0; t < 3; ++t) {
            if (t < NT) {
                const int nrow = 64 + (ntb + t) * 16 + col;   // (nrow&15)==col
                const short8 bf = *(const short8*)&S[nrow * 128 + (sc << 3)];
                acc[t] = __builtin_amdgcn_mfma_f32_16x16x32_bf16(af, bf, acc[t], 0, 0, 0);
            }
        }
    }

    // ---- epilogue: C/D layout col=lane&15, row=quad*4+reg; i = m + 63 - n ----
    float* obase = out + (size_t)(bh * W + j0) * 64;
    #pragma unroll
    for (int t = 0; t < 3; ++t) {
        if (t < NT) {
            const int n = (ntb + t) * 16 + col;
            #pragma unroll
            for (int r = 0; r < 4; ++r) {
                const int m = m0 + quad * 4 + r;
                const int i = m + 63 - n;
                if (i >= 0 && i < 64) {
                    obase[m * 64 + i] = acc[t][r] * 0.0078125f;   // /128
                }
            }
        }
    }
}

extern "C" void kernel_launch(void* const* d_in, const int* in_sizes, int n_in,
                              void* d_out, int out_size, void* d_ws, size_t ws_size,
                              hipStream_t stream) {
    const float* L = (const float*)d_in[0];
    const float* R = (const float*)d_in[1];
    float* out = (float*)d_out;
    dim3 grid(W / TJ, 8 * 160);   // (5, 1280)
    cost_volume_kernel<<<grid, 512, 0, stream>>>(L, R, out);
}